// Round 9
// baseline (268.285 us; speedup 1.0000x reference)
//
#include <hip/hip_runtime.h>
#include <hip/hip_bf16.h>
#include <stdint.h>
#include <math.h>

typedef unsigned short u16;
typedef uint32_t u32;
typedef __bf16 bf16x8 __attribute__((ext_vector_type(8)));
typedef float f32x4 __attribute__((ext_vector_type(4)));
typedef float f32x16 __attribute__((ext_vector_type(16)));
typedef u16 u16x8 __attribute__((ext_vector_type(8)));
typedef u16 u16x4 __attribute__((ext_vector_type(4)));

#define B_ 4
#define T_ 2048
#define D_ 1024
#define H_ 16
#define HD_ 64
#define M_ (B_*T_)

__device__ __forceinline__ u16 f2bf(float f) {
    union { __bf16 h; u16 u; } c;
    c.h = (__bf16)f;                 // RNE fptrunc
    return c.u;
}

__device__ __forceinline__ void gl16(const u16* g, u16* l) {
    __builtin_amdgcn_global_load_lds(
        (__attribute__((address_space(1))) void*)g,
        (__attribute__((address_space(3))) void*)l, 16, 0, 0);
}

__device__ __forceinline__ f32x4 mfma16(bf16x8 a, bf16x8 b, f32x4 c) {
    return __builtin_amdgcn_mfma_f32_16x16x32_bf16(a, b, c, 0, 0, 0);
}

__device__ __forceinline__ f32x16 mfma32(bf16x8 a, bf16x8 b, f32x16 c) {
    return __builtin_amdgcn_mfma_f32_32x32x16_bf16(a, b, c, 0, 0, 0);
}

__device__ __forceinline__ u32 cvtpk_bf16(float lo, float hi) {
    u32 r;
    asm("v_cvt_pk_bf16_f32 %0, %1, %2" : "=v"(r) : "v"(lo), "v"(hi));
    return r;
}

// raw v_exp_f32 (single instruction); logits bounded so HW semantics suffice.
__device__ __forceinline__ float fexp2(float x) {
    return __builtin_amdgcn_exp2f(x);
}

// ---------------- precast: fp32 -> bf16, exact flat grid (12288 blocks) ----------------
__global__ __launch_bounds__(256) void precast(
    const float* __restrict__ x,  const float* __restrict__ wq,
    const float* __restrict__ wk, const float* __restrict__ wv,
    const float* __restrict__ wo,
    u16* __restrict__ xb, u16* __restrict__ wqb, u16* __restrict__ wkb,
    u16* __restrict__ wvb, u16* __restrict__ wob)
{
    const int i = (blockIdx.x * 256 + threadIdx.x) * 4;   // element index
    const int nx = M_ * D_;                               // 8388608
    const float* src; u16* dst; int off;
    if (i < nx) { src = x; dst = xb; off = i; }
    else {
        int j = i - nx;
        int w = j >> 20;                                  // which weight
        off = j & ((1 << 20) - 1);
        switch (w) {
            case 0: src = wq; dst = wqb; break;
            case 1: src = wk; dst = wkb; break;
            case 2: src = wv; dst = wvb; break;
            default: src = wo; dst = wob; break;
        }
    }
    float4 v = *(const float4*)&src[off];
    u16x4 p = { f2bf(v.x), f2bf(v.y), f2bf(v.z), f2bf(v.w) };
    *(u16x4*)&dst[off] = p;
}

// ======== 8-wave pipelined GEMM: BM=256, BN=128, BK=64, 3-buf depth-2 ========
__device__ __forceinline__ void gemm8_pipe(
    const u16* __restrict__ Xg, const u16* __restrict__ Wg,
    u16* As, u16* Bs,
    const int tid, const int wm, const int wn, const int l15, const int quad,
    f32x4 acc[4][4])
{
    const u16* asrc[4]; int adst[4];
#pragma unroll
    for (int i = 0; i < 4; ++i) {
        int c = tid + i * 512;
        int row = c >> 3, slot = c & 7;
        asrc[i] = Xg + (size_t)row * 1024 + (slot ^ (row & 7)) * 8;
        adst[i] = c * 8;
    }
    const u16* bsrc[2]; int bdst[2];
#pragma unroll
    for (int i = 0; i < 2; ++i) {
        int c = tid + i * 512;
        int row = c >> 3, slot = c & 7;
        bsrc[i] = Wg + (size_t)row * 1024 + (slot ^ (row & 7)) * 8;
        bdst[i] = c * 8;
    }
    const int sw = l15 & 7;
    const int so0 = (quad ^ sw) * 8;
    const int so1 = ((4 + quad) ^ sw) * 8;

#pragma unroll
    for (int tt = 0; tt < 2; ++tt) {
#pragma unroll
        for (int i = 0; i < 4; ++i) gl16(asrc[i] + tt * 64, As + tt * 16384 + adst[i]);
#pragma unroll
        for (int i = 0; i < 2; ++i) gl16(bsrc[i] + tt * 64, Bs + tt * 8192 + bdst[i]);
    }
    asm volatile("s_waitcnt vmcnt(6)" ::: "memory");
    __builtin_amdgcn_s_barrier();

#pragma unroll
    for (int t = 0; t < 16; ++t) {
        const u16* Ab = As + (t % 3) * 16384;
        const u16* Bb = Bs + (t % 3) * 8192;
        if (t + 2 < 16) {
            const int k2 = (t + 2) * 64;
            u16* An = As + ((t + 2) % 3) * 16384;
            u16* Bn = Bs + ((t + 2) % 3) * 8192;
#pragma unroll
            for (int i = 0; i < 4; ++i) gl16(asrc[i] + k2, An + adst[i]);
#pragma unroll
            for (int i = 0; i < 2; ++i) gl16(bsrc[i] + k2, Bn + bdst[i]);
        }
        __builtin_amdgcn_sched_barrier(0);
        bf16x8 af0[4], af1[4], bf0[4], bf1[4];
#pragma unroll
        for (int mf = 0; mf < 4; ++mf) {
            const int rr = (wm * 64 + mf * 16 + l15) * 64;
            af0[mf] = *(const bf16x8*)&Ab[rr + so0];
            af1[mf] = *(const bf16x8*)&Ab[rr + so1];
        }
#pragma unroll
        for (int nf = 0; nf < 4; ++nf) {
            const int rr = (wn * 64 + nf * 16 + l15) * 64;
            bf0[nf] = *(const bf16x8*)&Bb[rr + so0];
            bf1[nf] = *(const bf16x8*)&Bb[rr + so1];
        }
        __builtin_amdgcn_s_setprio(1);
#pragma unroll
        for (int mf = 0; mf < 4; ++mf)
#pragma unroll
            for (int nf = 0; nf < 4; ++nf)
                acc[mf][nf] = mfma16(af0[mf], bf0[nf], acc[mf][nf]);
#pragma unroll
        for (int mf = 0; mf < 4; ++mf)
#pragma unroll
            for (int nf = 0; nf < 4; ++nf)
                acc[mf][nf] = mfma16(af1[mf], bf1[nf], acc[mf][nf]);
        __builtin_amdgcn_s_setprio(0);
        __builtin_amdgcn_sched_barrier(0);
        if (t + 2 < 16)      asm volatile("s_waitcnt vmcnt(6)" ::: "memory");
        else if (t + 1 < 16) asm volatile("s_waitcnt vmcnt(0)" ::: "memory");
        __builtin_amdgcn_s_barrier();
    }
}

// ---- merged QKV GEMM; V written directly in transposed [bh][hd][t] layout ----
__global__ __launch_bounds__(512, 2) void qkv_gemm(
    const u16* __restrict__ Xb, const u16* __restrict__ W3,
    u16* __restrict__ Qo, u16* __restrict__ Ko, u16* __restrict__ Vt)
{
    __shared__ __attribute__((aligned(16))) u16 As[3 * 256 * 64];   // 96KB
    __shared__ __attribute__((aligned(16))) u16 Bs[3 * 128 * 64];   // 48KB

    const int wg = blockIdx.x + 24 * blockIdx.y;   // [0,768)
    const int xcd = wg & 7, k = wg >> 3;           // k in [0,96)
    const int by = xcd * 4 + (k / 24);             // [0,32)
    const int bx = k % 24;                         // [0,24)
    const int n0 = bx * 128, m0 = by * 256;
    const u16* Xg = Xb + (size_t)m0 * 1024;
    const u16* Wg = W3 + (size_t)n0 * 1024;
    const int z = n0 >> 10;                        // 0:Q 1:K 2:V (block-uniform)
    const float qs = (z == 0) ? 0.125f * 1.44269504088896340736f : 1.0f;

    const int tid = threadIdx.x;
    const int lane = tid & 63;
    const int wave = tid >> 6;
    const int wm = wave >> 1, wn = wave & 1;       // 4m x 2n
    const int l15 = lane & 15, quad = lane >> 4;

    f32x4 acc[4][4];
#pragma unroll
    for (int i = 0; i < 4; ++i)
#pragma unroll
        for (int j = 0; j < 4; ++j) acc[i][j] = (f32x4){0.f, 0.f, 0.f, 0.f};

    gemm8_pipe(Xg, Wg, &As[0], &Bs[0], tid, wm, wn, l15, quad, acc);

    if (z == 2) {
        // V: write transposed Vt[bh][hd][t]; 4 consecutive t per lane -> u16x4
#pragma unroll
        for (int mf = 0; mf < 4; ++mf)
#pragma unroll
            for (int nf = 0; nf < 4; ++nf) {
                int row0 = m0 + wm * 64 + mf * 16 + quad * 4;
                int colz = (n0 & 1023) + wn * 64 + nf * 16 + l15;
                int b = row0 >> 11;
                int t = row0 & 2047;
                int h = colz >> 6;
                int hd = colz & 63;
                u16x4 pv = { f2bf(acc[mf][nf][0]), f2bf(acc[mf][nf][1]),
                             f2bf(acc[mf][nf][2]), f2bf(acc[mf][nf][3]) };
                *(u16x4*)&Vt[(((size_t)(b * H_ + h) * HD_ + hd)) * T_ + t] = pv;
            }
    } else {
        u16* Out = (z == 0) ? Qo : Ko;
#pragma unroll
        for (int mf = 0; mf < 4; ++mf)
#pragma unroll
            for (int nf = 0; nf < 4; ++nf)
#pragma unroll
                for (int r = 0; r < 4; ++r) {
                    int row = m0 + wm * 64 + mf * 16 + quad * 4 + r;
                    int colz = (n0 & 1023) + wn * 64 + nf * 16 + l15;
                    int b = row >> 11;
                    int t = row & 2047;
                    int h = colz >> 6;
                    int hd = colz & 63;
                    Out[((b * H_ + h) * T_ + t) * HD_ + hd] = f2bf(acc[mf][nf][r] * qs);
                }
    }
}

// ---- output projection: O[8192][1024] @ Wo^T + bo; grid (8, 32) x 512 ----
__global__ __launch_bounds__(512, 2) void out_gemm(
    const u16* __restrict__ Xb, const u16* __restrict__ W3,
    const float* __restrict__ bias, float* __restrict__ Out)
{
    __shared__ __attribute__((aligned(16))) u16 As[3 * 256 * 64];
    __shared__ __attribute__((aligned(16))) u16 Bs[3 * 128 * 64];

    const int wg = blockIdx.x + 8 * blockIdx.y;    // [0,256)
    const int xcd = wg & 7, k = wg >> 3;           // k in [0,32)
    const int by = xcd * 4 + (k / 8);              // [0,32)
    const int bx = k & 7;                          // [0,8)
    const int n0 = bx * 128, m0 = by * 256;
    const u16* Xg = Xb + (size_t)m0 * 1024;
    const u16* Wg = W3 + (size_t)n0 * 1024;

    const int tid = threadIdx.x;
    const int lane = tid & 63;
    const int wave = tid >> 6;
    const int wm = wave >> 1, wn = wave & 1;
    const int l15 = lane & 15, quad = lane >> 4;

    f32x4 acc[4][4];
#pragma unroll
    for (int i = 0; i < 4; ++i)
#pragma unroll
        for (int j = 0; j < 4; ++j) acc[i][j] = (f32x4){0.f, 0.f, 0.f, 0.f};

    gemm8_pipe(Xg, Wg, &As[0], &Bs[0], tid, wm, wn, l15, quad, acc);

#pragma unroll
    for (int mf = 0; mf < 4; ++mf)
#pragma unroll
        for (int nf = 0; nf < 4; ++nf)
#pragma unroll
            for (int r = 0; r < 4; ++r) {
                int row = m0 + wm * 64 + mf * 16 + quad * 4 + r;
                int col = n0 + wn * 64 + nf * 16 + l15;
                Out[(size_t)row * 1024 + col] = acc[mf][nf][r] + bias[col];
            }
}

// ---- Flash attention: 512 Q-rows/block (8 waves), 3-buf depth-2 counted vmcnt ----
// Per wave: 64 Q-rows (identical register layout to the 92us R6 kernel).
// 256 blocks = 1/CU; tile-scans halve vs R6 -> DS + staging traffic halve.
// Each thread stages exactly 1 K-chunk + 1 V-chunk per tile (512 thr x 16B = 8KB).
__global__ __launch_bounds__(512, 2) void attn(
    const u16* __restrict__ Q, const u16* __restrict__ K,
    const u16* __restrict__ Vt_g, u16* __restrict__ O)
{
    __shared__ __attribute__((aligned(16))) u16 Ks[3 * 4096];   // 3-buf [64 s][64 d]
    __shared__ __attribute__((aligned(16))) u16 Vts[3 * 4096];  // 3-buf [64 d][64 s]
    __shared__ float lps[8 * 64];

    const int tid = threadIdx.x;
    const int lane = tid & 63, w = tid >> 6;
    const int l31 = lane & 31, hi = lane >> 5;

    // XCD remap: 256 blocks; each XCD owns 8 bh x 4 Q-blocks
    const int wg = blockIdx.x + (T_ / 512) * (blockIdx.y + H_ * blockIdx.z); // [0,256)
    const int xcd = wg & 7, k8 = wg >> 3;          // k8 in [0,32)
    const int bh = xcd + 8 * (k8 >> 2);            // [0,64)
    const int xq = k8 & 3;                         // Q-block within bh
    const int b = bh >> 4, h = bh & 15;
    const int t0 = xq * 512 + w * 64;

    const size_t base = (size_t)bh * T_ * HD_;
    const u16* Kb = K + base;
    const u16* Vtb = Vt_g + base;
    const u16* Qb = Q + base + (size_t)t0 * HD_;

    // staging: 1 chunk each of K and V per thread; pre-swizzled source
    const int ra = tid >> 3, sa = (tid & 7) ^ (ra & 7);
    const u16* kp = Kb  + (size_t)ra * 64 + sa * 8;   // + s0*64
    const u16* vp = Vtb + (size_t)ra * T_ + sa * 8;   // + s0
    const int ldst = tid * 8;

    int foff[2][4];
#pragma unroll
    for (int nt = 0; nt < 2; ++nt) {
        const int row = nt * 32 + l31;
#pragma unroll
        for (int kb = 0; kb < 4; ++kb)
            foff[nt][kb] = row * 64 + (((kb * 2 + hi) ^ (row & 7)) * 8);
    }

    bf16x8 qf[2][4];
#pragma unroll
    for (int qt = 0; qt < 2; ++qt)
#pragma unroll
        for (int kb = 0; kb < 4; ++kb)
            qf[qt][kb] = *(const bf16x8*)&Qb[(qt * 32 + l31) * 64 + kb * 16 + hi * 8];

    f32x16 zacc;
#pragma unroll
    for (int i = 0; i < 16; ++i) zacc[i] = 0.f;
    f32x16 oacc[2][2];
#pragma unroll
    for (int qt = 0; qt < 2; ++qt)
#pragma unroll
        for (int cb = 0; cb < 2; ++cb) oacc[qt][cb] = zacc;
    float lp[2] = {0.f, 0.f};

    // prologue: stage tiles 0,1 -> bufs 0,1
#pragma unroll
    for (int tt = 0; tt < 2; ++tt) {
        gl16(kp + (size_t)tt * 64 * 64, &Ks[tt * 4096 + ldst]);
        gl16(vp + (size_t)tt * 64,      &Vts[tt * 4096 + ldst]);
    }
    asm volatile("s_waitcnt vmcnt(2)" ::: "memory");   // tile 0 landed
    __builtin_amdgcn_s_barrier();

    int cur = 0, nx2 = 2;
    for (int t = 0; t < 32; ++t) {
        if (t + 2 < 32) {                // stage tile t+2 into buf nx2
            const size_t so = (size_t)(t + 2) * 64;
            gl16(kp + so * 64, &Ks[nx2 * 4096 + ldst]);
            gl16(vp + so,      &Vts[nx2 * 4096 + ldst]);
        }
        __builtin_amdgcn_sched_barrier(0);
        const u16* Kc = &Ks[cur * 4096];
        const u16* Vc = &Vts[cur * 4096];

        bf16x8 pa[2][4];
#pragma unroll
        for (int nt = 0; nt < 2; ++nt) {
            bf16x8 kf[4];
#pragma unroll
            for (int kb = 0; kb < 4; ++kb)
                kf[kb] = *(const bf16x8*)&Kc[foff[nt][kb]];
#pragma unroll
            for (int qt = 0; qt < 2; ++qt) {
                __builtin_amdgcn_s_setprio(1);
                f32x16 sacc = mfma32(kf[0], qf[qt][0], zacc);
                sacc = mfma32(kf[1], qf[qt][1], sacc);
                sacc = mfma32(kf[2], qf[qt][2], sacc);
                sacc = mfma32(kf[3], qf[qt][3], sacc);
                __builtin_amdgcn_s_setprio(0);
                float p[16];
#pragma unroll
                for (int r = 0; r < 16; ++r) p[r] = fexp2(sacc[r]);
                float s01 = (p[0] + p[1]) + (p[2] + p[3]);
                float s23 = (p[4] + p[5]) + (p[6] + p[7]);
                float s45 = (p[8] + p[9]) + (p[10] + p[11]);
                float s67 = (p[12] + p[13]) + (p[14] + p[15]);
                lp[qt] += (s01 + s23) + (s45 + s67);
#pragma unroll
                for (int c = 0; c < 2; ++c) {
                    const int g = c * 8;
                    u32 a0 = cvtpk_bf16(p[g + 0], p[g + 1]);
                    u32 a1 = cvtpk_bf16(p[g + 2], p[g + 3]);
                    u32 b0 = cvtpk_bf16(p[g + 4], p[g + 5]);
                    u32 b1 = cvtpk_bf16(p[g + 6], p[g + 7]);
                    asm("v_permlane32_swap_b32 %0, %1" : "+v"(a0), "+v"(b0));
                    asm("v_permlane32_swap_b32 %0, %1" : "+v"(a1), "+v"(b1));
                    union { u32 wq[4]; bf16x8 v; } uu;
                    uu.wq[0] = a0; uu.wq[1] = a1; uu.wq[2] = b0; uu.wq[3] = b1;
                    pa[qt][nt * 2 + c] = uu.v;
                }
            }
        }
        __builtin_amdgcn_s_setprio(1);
#pragma unroll
        for (int cb = 0; cb < 2; ++cb)
#pragma unroll
            for (int kb = 0; kb < 4; ++kb) {
                bf16x8 vf = *(const bf16x8*)&Vc[foff[cb][kb]];
                oacc[0][cb] = mfma32(pa[0][kb], vf, oacc[0][cb]);
                oacc[1][cb] = mfma32(pa[1][kb], vf, oacc[1][cb]);
            }
        __builtin_amdgcn_s_setprio(0);
        __builtin_amdgcn_sched_barrier(0);
        if (t + 2 < 32)      asm volatile("s_waitcnt vmcnt(2)" ::: "memory"); // t+1 landed
        else if (t + 1 < 32) asm volatile("s_waitcnt vmcnt(0)" ::: "memory");
        __builtin_amdgcn_s_barrier();
        cur = (cur == 2) ? 0 : cur + 1;
        nx2 = (nx2 == 2) ? 0 : nx2 + 1;
    }

#pragma unroll
    for (int qt = 0; qt < 2; ++qt) {
        lp[qt] += __shfl_xor(lp[qt], 32);
        lps[w * 64 + qt * 32 + l31] = lp[qt];
    }
    asm volatile("s_waitcnt lgkmcnt(0)" ::: "memory");

#pragma unroll
    for (int qt = 0; qt < 2; ++qt)
#pragma unroll
        for (int r = 0; r < 16; ++r) {
            const int trow = (r & 3) + 8 * (r >> 2) + 4 * hi;
            const float dn = 1.f / lps[w * 64 + qt * 32 + trow];
            const int t = t0 + qt * 32 + trow;
#pragma unroll
            for (int cb = 0; cb < 2; ++cb) {
                const int col = h * 64 + cb * 32 + l31;
                O[((size_t)b * T_ + t) * D_ + col] = f2bf(oacc[qt][cb][r] * dn);
            }
        }
}

extern "C" void kernel_launch(void* const* d_in, const int* in_sizes, int n_in,
                              void* d_out, int out_size, void* d_ws, size_t ws_size,
                              hipStream_t stream) {
    const float* x  = (const float*)d_in[0];
    const float* Wq = (const float*)d_in[1];
    const float* Wk = (const float*)d_in[2];
    const float* Wv = (const float*)d_in[3];
    const float* Wo = (const float*)d_in[4];
    const float* bo = (const float*)d_in[5];
    float* out = (float*)d_out;

    const size_t n_qkv = (size_t)B_ * H_ * T_ * HD_;  // 8388608
    const size_t n_w   = (size_t)D_ * D_;             // 1048576
    u16* Qw   = (u16*)d_ws;
    u16* Kw   = Qw + n_qkv;
    u16* Vtw  = Kw + n_qkv;    // V written transposed [bh][hd][t] directly by qkv_gemm
    u16* XbOw = Vtw + n_qkv;   // Xb during precast/qkv; Ow (attn output) after
    u16* Xb   = XbOw;
    u16* Ow   = XbOw;
    u16* Wqb  = XbOw + n_qkv;  // Wq,Wk,Wv contiguous => single [3072][1024] matrix
    u16* Wkb  = Wqb + n_w;
    u16* Wvb  = Wkb + n_w;
    u16* Wob  = Wvb + n_w;

    dim3 gc(12288);            // exact: (8.4M + 4x1M)/4/256
    precast<<<gc, 256, 0, stream>>>(x, Wq, Wk, Wv, Wo, Xb, Wqb, Wkb, Wvb, Wob);

    dim3 g1(3072 / 128, M_ / 256);
    qkv_gemm<<<g1, 512, 0, stream>>>(Xb, Wqb, Qw, Kw, Vtw);

    dim3 g2(T_ / 512, H_, B_);
    attn<<<g2, 512, 0, stream>>>(Qw, Kw, Vtw, Ow);

    dim3 g3(1024 / 128, M_ / 256);
    out_gemm<<<g3, 512, 0, stream>>>(Ow, Wob, bo, out);
}

// Round 10
// 248.437 us; speedup vs baseline: 1.0799x; 1.0799x over previous
//
#include <hip/hip_runtime.h>
#include <hip/hip_bf16.h>
#include <stdint.h>
#include <math.h>

typedef unsigned short u16;
typedef uint32_t u32;
typedef __bf16 bf16x8 __attribute__((ext_vector_type(8)));
typedef float f32x4 __attribute__((ext_vector_type(4)));
typedef float f32x16 __attribute__((ext_vector_type(16)));
typedef u16 u16x8 __attribute__((ext_vector_type(8)));
typedef u16 u16x4 __attribute__((ext_vector_type(4)));

#define B_ 4
#define T_ 2048
#define D_ 1024
#define H_ 16
#define HD_ 64
#define M_ (B_*T_)

__device__ __forceinline__ u16 f2bf(float f) {
    union { __bf16 h; u16 u; } c;
    c.h = (__bf16)f;                 // RNE fptrunc
    return c.u;
}

__device__ __forceinline__ void gl16(const u16* g, u16* l) {
    __builtin_amdgcn_global_load_lds(
        (__attribute__((address_space(1))) void*)g,
        (__attribute__((address_space(3))) void*)l, 16, 0, 0);
}

__device__ __forceinline__ f32x4 mfma16(bf16x8 a, bf16x8 b, f32x4 c) {
    return __builtin_amdgcn_mfma_f32_16x16x32_bf16(a, b, c, 0, 0, 0);
}

__device__ __forceinline__ f32x16 mfma32(bf16x8 a, bf16x8 b, f32x16 c) {
    return __builtin_amdgcn_mfma_f32_32x32x16_bf16(a, b, c, 0, 0, 0);
}

__device__ __forceinline__ u32 cvtpk_bf16(float lo, float hi) {
    u32 r;
    asm("v_cvt_pk_bf16_f32 %0, %1, %2" : "=v"(r) : "v"(lo), "v"(hi));
    return r;
}

// raw v_exp_f32 (single instruction); logits bounded so HW semantics suffice.
__device__ __forceinline__ float fexp2(float x) {
    return __builtin_amdgcn_exp2f(x);
}

// ---------------- precast: fp32 -> bf16, exact flat grid (12288 blocks) ----------------
__global__ __launch_bounds__(256) void precast(
    const float* __restrict__ x,  const float* __restrict__ wq,
    const float* __restrict__ wk, const float* __restrict__ wv,
    const float* __restrict__ wo,
    u16* __restrict__ xb, u16* __restrict__ wqb, u16* __restrict__ wkb,
    u16* __restrict__ wvb, u16* __restrict__ wob)
{
    const int i = (blockIdx.x * 256 + threadIdx.x) * 4;   // element index
    const int nx = M_ * D_;                               // 8388608
    const float* src; u16* dst; int off;
    if (i < nx) { src = x; dst = xb; off = i; }
    else {
        int j = i - nx;
        int w = j >> 20;                                  // which weight
        off = j & ((1 << 20) - 1);
        switch (w) {
            case 0: src = wq; dst = wqb; break;
            case 1: src = wk; dst = wkb; break;
            case 2: src = wv; dst = wvb; break;
            default: src = wo; dst = wob; break;
        }
    }
    float4 v = *(const float4*)&src[off];
    u16x4 p = { f2bf(v.x), f2bf(v.y), f2bf(v.z), f2bf(v.w) };
    *(u16x4*)&dst[off] = p;
}

// ======== 8-wave GEMM: BM=256, BN=128, BK=32, 3-buf depth-2, 72KB LDS ========
// 2 blocks/CU (m132 lesson: occupancy > barrier amortization). 8 waves 4m x 2n,
// per-wave output 64x64 (4x4 frags), 16 mfma16 + 8 ds_read_b128 per tile.
// Chunk swizzle: LDS slot s of row r holds global chunk s^((r>>1)&3) -> wave
// b128 reads are 8 dwords/bank uniform. One barrier + counted vmcnt(3) per tile.
__device__ __forceinline__ void gemm32_pipe(
    const u16* __restrict__ Xg, const u16* __restrict__ Wg,
    u16* As, u16* Bs,
    const int tid, const int wm, const int wn, const int l15, const int quad,
    f32x4 acc[4][4])
{
    const u16* asrc[2]; int adst[2];
#pragma unroll
    for (int i = 0; i < 2; ++i) {
        int c = tid + i * 512;                   // [0,1024) chunks of A tile
        int row = c >> 2, slot = c & 3;
        int xs = slot ^ ((row >> 1) & 3);
        asrc[i] = Xg + (size_t)row * 1024 + xs * 8;
        adst[i] = c * 8;
    }
    const u16* bsrc; int bdst;
    {
        int c = tid;                             // [0,512) chunks of B tile
        int row = c >> 2, slot = c & 3;
        int xs = slot ^ ((row >> 1) & 3);
        bsrc = Wg + (size_t)row * 1024 + xs * 8;
        bdst = c * 8;
    }
    const int so = (quad ^ ((l15 >> 1) & 3)) * 8;   // lane-constant read slot

    // prologue: tiles 0,1 -> bufs 0,1 (3 gl16 per thread per tile)
#pragma unroll
    for (int tt = 0; tt < 2; ++tt) {
#pragma unroll
        for (int i = 0; i < 2; ++i) gl16(asrc[i] + tt * 32, As + tt * 8192 + adst[i]);
        gl16(bsrc + tt * 32, Bs + tt * 4096 + bdst);
    }
    asm volatile("s_waitcnt vmcnt(3)" ::: "memory");   // tile 0 landed
    __builtin_amdgcn_s_barrier();

#pragma unroll
    for (int t = 0; t < 32; ++t) {
        const u16* Ab = As + (t % 3) * 8192;
        const u16* Bb = Bs + (t % 3) * 4096;
        if (t + 2 < 32) {                      // stage tile t+2 into buf (t+2)%3
            const int k2 = (t + 2) * 32;
            u16* An = As + ((t + 2) % 3) * 8192;
            u16* Bn = Bs + ((t + 2) % 3) * 4096;
#pragma unroll
            for (int i = 0; i < 2; ++i) gl16(asrc[i] + k2, An + adst[i]);
            gl16(bsrc + k2, Bn + bdst);
        }
        __builtin_amdgcn_sched_barrier(0);     // staging issued first
        bf16x8 af[4], bfr[4];
#pragma unroll
        for (int mf = 0; mf < 4; ++mf)
            af[mf] = *(const bf16x8*)&Ab[(wm * 64 + mf * 16 + l15) * 32 + so];
#pragma unroll
        for (int nf = 0; nf < 4; ++nf)
            bfr[nf] = *(const bf16x8*)&Bb[(wn * 64 + nf * 16 + l15) * 32 + so];
        __builtin_amdgcn_s_setprio(1);
#pragma unroll
        for (int mf = 0; mf < 4; ++mf)
#pragma unroll
            for (int nf = 0; nf < 4; ++nf)
                acc[mf][nf] = mfma16(af[mf], bfr[nf], acc[mf][nf]);
        __builtin_amdgcn_s_setprio(0);
        __builtin_amdgcn_sched_barrier(0);
        if (t + 2 < 32)      asm volatile("s_waitcnt vmcnt(3)" ::: "memory"); // t+1 landed
        else if (t + 1 < 32) asm volatile("s_waitcnt vmcnt(0)" ::: "memory");
        __builtin_amdgcn_s_barrier();
    }
}

// ---- merged QKV GEMM; V written directly in transposed [bh][hd][t] layout ----
__global__ __launch_bounds__(512, 4) void qkv_gemm(
    const u16* __restrict__ Xb, const u16* __restrict__ W3,
    u16* __restrict__ Qo, u16* __restrict__ Ko, u16* __restrict__ Vt)
{
    __shared__ __attribute__((aligned(16))) u16 As[3 * 256 * 32];   // 48KB
    __shared__ __attribute__((aligned(16))) u16 Bs[3 * 128 * 32];   // 24KB

    const int wg = blockIdx.x + 24 * blockIdx.y;   // [0,768)
    const int xcd = wg & 7, k = wg >> 3;           // k in [0,96)
    const int by = xcd * 4 + (k / 24);             // [0,32)
    const int bx = k % 24;                         // [0,24)
    const int n0 = bx * 128, m0 = by * 256;
    const u16* Xg = Xb + (size_t)m0 * 1024;
    const u16* Wg = W3 + (size_t)n0 * 1024;
    const int z = n0 >> 10;                        // 0:Q 1:K 2:V (block-uniform)
    const float qs = (z == 0) ? 0.125f * 1.44269504088896340736f : 1.0f;

    const int tid = threadIdx.x;
    const int lane = tid & 63;
    const int wave = tid >> 6;
    const int wm = wave >> 1, wn = wave & 1;       // 4m x 2n
    const int l15 = lane & 15, quad = lane >> 4;

    f32x4 acc[4][4];
#pragma unroll
    for (int i = 0; i < 4; ++i)
#pragma unroll
        for (int j = 0; j < 4; ++j) acc[i][j] = (f32x4){0.f, 0.f, 0.f, 0.f};

    gemm32_pipe(Xg, Wg, &As[0], &Bs[0], tid, wm, wn, l15, quad, acc);

    if (z == 2) {
        // V: write transposed Vt[bh][hd][t]; 4 consecutive t per lane -> u16x4
#pragma unroll
        for (int mf = 0; mf < 4; ++mf)
#pragma unroll
            for (int nf = 0; nf < 4; ++nf) {
                int row0 = m0 + wm * 64 + mf * 16 + quad * 4;
                int colz = (n0 & 1023) + wn * 64 + nf * 16 + l15;
                int b = row0 >> 11;
                int t = row0 & 2047;
                int h = colz >> 6;
                int hd = colz & 63;
                u16x4 pv = { f2bf(acc[mf][nf][0]), f2bf(acc[mf][nf][1]),
                             f2bf(acc[mf][nf][2]), f2bf(acc[mf][nf][3]) };
                *(u16x4*)&Vt[(((size_t)(b * H_ + h) * HD_ + hd)) * T_ + t] = pv;
            }
    } else {
        u16* Out = (z == 0) ? Qo : Ko;
#pragma unroll
        for (int mf = 0; mf < 4; ++mf)
#pragma unroll
            for (int nf = 0; nf < 4; ++nf)
#pragma unroll
                for (int r = 0; r < 4; ++r) {
                    int row = m0 + wm * 64 + mf * 16 + quad * 4 + r;
                    int colz = (n0 & 1023) + wn * 64 + nf * 16 + l15;
                    int b = row >> 11;
                    int t = row & 2047;
                    int h = colz >> 6;
                    int hd = colz & 63;
                    Out[((b * H_ + h) * T_ + t) * HD_ + hd] = f2bf(acc[mf][nf][r] * qs);
                }
    }
}

// ---- output projection: O[8192][1024] @ Wo^T + bo; grid (8, 32) x 512 ----
__global__ __launch_bounds__(512, 4) void out_gemm(
    const u16* __restrict__ Xb, const u16* __restrict__ W3,
    const float* __restrict__ bias, float* __restrict__ Out)
{
    __shared__ __attribute__((aligned(16))) u16 As[3 * 256 * 32];
    __shared__ __attribute__((aligned(16))) u16 Bs[3 * 128 * 32];

    const int wg = blockIdx.x + 8 * blockIdx.y;    // [0,256)
    const int xcd = wg & 7, k = wg >> 3;           // k in [0,32)
    const int by = xcd * 4 + (k / 8);              // [0,32)
    const int bx = k & 7;                          // [0,8)
    const int n0 = bx * 128, m0 = by * 256;
    const u16* Xg = Xb + (size_t)m0 * 1024;
    const u16* Wg = W3 + (size_t)n0 * 1024;

    const int tid = threadIdx.x;
    const int lane = tid & 63;
    const int wave = tid >> 6;
    const int wm = wave >> 1, wn = wave & 1;
    const int l15 = lane & 15, quad = lane >> 4;

    f32x4 acc[4][4];
#pragma unroll
    for (int i = 0; i < 4; ++i)
#pragma unroll
        for (int j = 0; j < 4; ++j) acc[i][j] = (f32x4){0.f, 0.f, 0.f, 0.f};

    gemm32_pipe(Xg, Wg, &As[0], &Bs[0], tid, wm, wn, l15, quad, acc);

#pragma unroll
    for (int mf = 0; mf < 4; ++mf)
#pragma unroll
        for (int nf = 0; nf < 4; ++nf)
#pragma unroll
            for (int r = 0; r < 4; ++r) {
                int row = m0 + wm * 64 + mf * 16 + quad * 4 + r;
                int col = n0 + wn * 64 + nf * 16 + l15;
                Out[(size_t)row * 1024 + col] = acc[mf][nf][r] + bias[col];
            }
}

// ---- Flash attention: 512 Q-rows/block, 3-buf depth-2, NO setprio (m190) ----
__global__ __launch_bounds__(512, 2) void attn(
    const u16* __restrict__ Q, const u16* __restrict__ K,
    const u16* __restrict__ Vt_g, u16* __restrict__ O)
{
    __shared__ __attribute__((aligned(16))) u16 Ks[3 * 4096];   // 3-buf [64 s][64 d]
    __shared__ __attribute__((aligned(16))) u16 Vts[3 * 4096];  // 3-buf [64 d][64 s]
    __shared__ float lps[8 * 64];

    const int tid = threadIdx.x;
    const int lane = tid & 63, w = tid >> 6;
    const int l31 = lane & 31, hi = lane >> 5;

    const int wg = blockIdx.x + (T_ / 512) * (blockIdx.y + H_ * blockIdx.z); // [0,256)
    const int xcd = wg & 7, k8 = wg >> 3;          // k8 in [0,32)
    const int bh = xcd + 8 * (k8 >> 2);            // [0,64)
    const int xq = k8 & 3;                         // Q-block within bh
    const int b = bh >> 4, h = bh & 15;
    const int t0 = xq * 512 + w * 64;

    const size_t base = (size_t)bh * T_ * HD_;
    const u16* Kb = K + base;
    const u16* Vtb = Vt_g + base;
    const u16* Qb = Q + base + (size_t)t0 * HD_;

    const int ra = tid >> 3, sa = (tid & 7) ^ (ra & 7);
    const u16* kp = Kb  + (size_t)ra * 64 + sa * 8;   // + s0*64
    const u16* vp = Vtb + (size_t)ra * T_ + sa * 8;   // + s0
    const int ldst = tid * 8;

    int foff[2][4];
#pragma unroll
    for (int nt = 0; nt < 2; ++nt) {
        const int row = nt * 32 + l31;
#pragma unroll
        for (int kb = 0; kb < 4; ++kb)
            foff[nt][kb] = row * 64 + (((kb * 2 + hi) ^ (row & 7)) * 8);
    }

    bf16x8 qf[2][4];
#pragma unroll
    for (int qt = 0; qt < 2; ++qt)
#pragma unroll
        for (int kb = 0; kb < 4; ++kb)
            qf[qt][kb] = *(const bf16x8*)&Qb[(qt * 32 + l31) * 64 + kb * 16 + hi * 8];

    f32x16 zacc;
#pragma unroll
    for (int i = 0; i < 16; ++i) zacc[i] = 0.f;
    f32x16 oacc[2][2];
#pragma unroll
    for (int qt = 0; qt < 2; ++qt)
#pragma unroll
        for (int cb = 0; cb < 2; ++cb) oacc[qt][cb] = zacc;
    float lp[2] = {0.f, 0.f};

#pragma unroll
    for (int tt = 0; tt < 2; ++tt) {
        gl16(kp + (size_t)tt * 64 * 64, &Ks[tt * 4096 + ldst]);
        gl16(vp + (size_t)tt * 64,      &Vts[tt * 4096 + ldst]);
    }
    asm volatile("s_waitcnt vmcnt(2)" ::: "memory");   // tile 0 landed
    __builtin_amdgcn_s_barrier();

    int cur = 0, nx2 = 2;
    for (int t = 0; t < 32; ++t) {
        if (t + 2 < 32) {                // stage tile t+2 into buf nx2
            const size_t so = (size_t)(t + 2) * 64;
            gl16(kp + so * 64, &Ks[nx2 * 4096 + ldst]);
            gl16(vp + so,      &Vts[nx2 * 4096 + ldst]);
        }
        __builtin_amdgcn_sched_barrier(0);
        const u16* Kc = &Ks[cur * 4096];
        const u16* Vc = &Vts[cur * 4096];

        bf16x8 pa[2][4];
#pragma unroll
        for (int nt = 0; nt < 2; ++nt) {
            bf16x8 kf[4];
#pragma unroll
            for (int kb = 0; kb < 4; ++kb)
                kf[kb] = *(const bf16x8*)&Kc[foff[nt][kb]];
#pragma unroll
            for (int qt = 0; qt < 2; ++qt) {
                f32x16 sacc = mfma32(kf[0], qf[qt][0], zacc);
                sacc = mfma32(kf[1], qf[qt][1], sacc);
                sacc = mfma32(kf[2], qf[qt][2], sacc);
                sacc = mfma32(kf[3], qf[qt][3], sacc);
                float p[16];
#pragma unroll
                for (int r = 0; r < 16; ++r) p[r] = fexp2(sacc[r]);
                float s01 = (p[0] + p[1]) + (p[2] + p[3]);
                float s23 = (p[4] + p[5]) + (p[6] + p[7]);
                float s45 = (p[8] + p[9]) + (p[10] + p[11]);
                float s67 = (p[12] + p[13]) + (p[14] + p[15]);
                lp[qt] += (s01 + s23) + (s45 + s67);
#pragma unroll
                for (int c = 0; c < 2; ++c) {
                    const int g = c * 8;
                    u32 a0 = cvtpk_bf16(p[g + 0], p[g + 1]);
                    u32 a1 = cvtpk_bf16(p[g + 2], p[g + 3]);
                    u32 b0 = cvtpk_bf16(p[g + 4], p[g + 5]);
                    u32 b1 = cvtpk_bf16(p[g + 6], p[g + 7]);
                    asm("v_permlane32_swap_b32 %0, %1" : "+v"(a0), "+v"(b0));
                    asm("v_permlane32_swap_b32 %0, %1" : "+v"(a1), "+v"(b1));
                    union { u32 wq[4]; bf16x8 v; } uu;
                    uu.wq[0] = a0; uu.wq[1] = a1; uu.wq[2] = b0; uu.wq[3] = b1;
                    pa[qt][nt * 2 + c] = uu.v;
                }
            }
        }
#pragma unroll
        for (int cb = 0; cb < 2; ++cb)
#pragma unroll
            for (int kb = 0; kb < 4; ++kb) {
                bf16x8 vf = *(const bf16x8*)&Vc[foff[cb][kb]];
                oacc[0][cb] = mfma32(pa[0][kb], vf, oacc[0][cb]);
                oacc[1][cb] = mfma32(pa[1][kb], vf, oacc[1][cb]);
            }
        __builtin_amdgcn_sched_barrier(0);
        if (t + 2 < 32)      asm volatile("s_waitcnt vmcnt(2)" ::: "memory"); // t+1 landed
        else if (t + 1 < 32) asm volatile("s_waitcnt vmcnt(0)" ::: "memory");
        __builtin_amdgcn_s_barrier();
        cur = (cur == 2) ? 0 : cur + 1;
        nx2 = (nx2 == 2) ? 0 : nx2 + 1;
    }

#pragma unroll
    for (int qt = 0; qt < 2; ++qt) {
        lp[qt] += __shfl_xor(lp[qt], 32);
        lps[w * 64 + qt * 32 + l31] = lp[qt];
    }
    asm volatile("s_waitcnt lgkmcnt(0)" ::: "memory");

#pragma unroll
    for (int qt = 0; qt < 2; ++qt)
#pragma unroll
        for (int r = 0; r < 16; ++r) {
            const int trow = (r & 3) + 8 * (r >> 2) + 4 * hi;
            const float dn = 1.f / lps[w * 64 + qt * 32 + trow];
            const int t = t0 + qt * 32 + trow;
#pragma unroll
            for (int cb = 0; cb < 2; ++cb) {
                const int col = h * 64 + cb * 32 + l31;
                O[((size_t)b * T_ + t) * D_ + col] = f2bf(oacc[qt][cb][r] * dn);
            }
        }
}

extern "C" void kernel_launch(void* const* d_in, const int* in_sizes, int n_in,
                              void* d_out, int out_size, void* d_ws, size_t ws_size,
                              hipStream_t stream) {
    const float* x  = (const float*)d_in[0];
    const float* Wq = (const float*)d_in[1];
    const float* Wk = (const float*)d_in[2];
    const float* Wv = (const float*)d_in[3];
    const float* Wo = (const float*)d_in[4];
    const float* bo = (const float*)d_in[5];
    float* out = (float*)d_out;

    const size_t n_qkv = (size_t)B_ * H_ * T_ * HD_;  // 8388608
    const size_t n_w   = (size_t)D_ * D_;             // 1048576
    u16* Qw   = (u16*)d_ws;
    u16* Kw   = Qw + n_qkv;
    u16* Vtw  = Kw + n_qkv;    // V written transposed [bh][hd][t] directly by qkv_gemm
    u16* XbOw = Vtw + n_qkv;   // Xb during precast/qkv; Ow (attn output) after
    u16* Xb   = XbOw;
    u16* Ow   = XbOw;
    u16* Wqb  = XbOw + n_qkv;  // Wq,Wk,Wv contiguous => single [3072][1024] matrix
    u16* Wkb  = Wqb + n_w;
    u16* Wvb  = Wkb + n_w;
    u16* Wob  = Wvb + n_w;

    dim3 gc(12288);            // exact: (8.4M + 4x1M)/4/256
    precast<<<gc, 256, 0, stream>>>(x, Wq, Wk, Wv, Wo, Xb, Wqb, Wkb, Wvb, Wob);

    dim3 g1(3072 / 128, M_ / 256);
    qkv_gemm<<<g1, 512, 0, stream>>>(Xb, Wqb, Qw, Kw, Vtw);

    dim3 g2(T_ / 512, H_, B_);
    attn<<<g2, 512, 0, stream>>>(Qw, Kw, Vtw, Ow);

    dim3 g3(1024 / 128, M_ / 256);
    out_gemm<<<g3, 512, 0, stream>>>(Ow, Wob, bo, out);
}